// Round 17
// baseline (735.617 us; speedup 1.0000x reference)
//
#include <hip/hip_runtime.h>

#define T_STEPS 4
#define BATCH   8
#define C_IN    64
#define C_OUT   64
#define HH      128
#define WW      128
#define TH      8           // block tile height (2 wave-strips of 4)
#define TW      16
#define ROWS    (TH + 2)    // 10
#define COLS    18          // staged columns (halo)
#define RLEN    24          // padded row pitch (words) -> measured-conflict-free b32 pattern
#define NELEM   (C_IN * ROWS * COLS)    // 11520
#define NIT     ((NELEM + 511) / 512)   // 23 staging rounds per thread

// f32 rounding of math.exp(-0.5)
#define DECAY_F32 0.6065306597126334f

// Weight re-layout: w[co][ci][ky][kx] -> wt[j][ci][co], j = ky*3+kx
__global__ void wt_build_kernel(const float* __restrict__ w, float* __restrict__ wt) {
    int tid = blockIdx.x * blockDim.x + threadIdx.x;
    if (tid >= 9 * C_IN * C_OUT) return;
    int co = tid & 63;
    int ci = (tid >> 6) & 63;
    int j  = tid >> 12;
    wt[tid] = w[(co * C_IN + ci) * 9 + j];
}

// Exact replica of the reference f32 arithmetic (probe-verified variant A):
// per output: seq FMA chain over (ky,kx, ci-innermost); cb = acc+bias;
// vt = v*DECAY + cb (separate rounded mul/add); spike = vt>1; soft reset.
//
// r12 configuration (16 co/lane, b32 pitch-24 LDS reads = the measured
// conflict-free pattern, SGPR weights) + async staging: per-thread stage
// offsets precomputed once; each t issues the NEXT t's 23 global loads into
// registers BEFORE the compute phase (latency hidden under ~40us of FMA),
// then ds_writes them after the post-compute barrier.
__global__ __launch_bounds__(512, 2) void snn_exact_kernel(
    const float* __restrict__ x,    // [T,B,C_IN,H,W]
    const float* __restrict__ wt,   // [9][C_IN][C_OUT]
    const float* __restrict__ bias, // [C_OUT]
    float* __restrict__ out)        // [T,B,C_OUT,H,W]
{
    __shared__ __align__(16) float sx[C_IN][ROWS][RLEN];   // 61440 B

    const int tid  = threadIdx.x;
    const int wid  = __builtin_amdgcn_readfirstlane(tid >> 6); // 0..7 (SGPR)
    const int lane = tid & 63;
    const int y    = lane & 3;          // 0..3 within strip
    const int xcol = lane >> 2;         // 0..15
    const int sy   = (wid >> 2) << 2;   // strip base: 0 or 4
    const int cob  = (wid & 3) << 4;    // wave's co base: 0,16,32,48
    const int b    = blockIdx.z;
    const int gy0  = blockIdx.y * TH;
    const int gx0  = blockIdx.x * TW;

    const float* bp = bias + cob;       // wave-uniform -> SGPR

    // ---- precompute staging offsets (t-invariant) ----
    // goff[k]: element offset within x's per-(t,b) 64-plane slab; bit31 = zero-fill.
    // loff: packed u16 LDS word offsets. Out-of-range threads / padded taps target
    // the col-18 pad slot (never read by TAP) with value 0 -> benign.
    unsigned goff[NIT];
    unsigned loff[(NIT + 1) / 2];
#pragma unroll
    for (int k = 0; k < NIT; ++k) {
        int e = tid + k * 512;
        unsigned g = 0x80000000u;
        unsigned l = 18;                 // pad slot
        if (e < NELEM) {
            int ci  = e / (ROWS * COLS);
            int rem = e - ci * (ROWS * COLS);
            int row = rem / COLS;
            int col = rem - row * COLS;
            int gy  = gy0 + row - 1;
            int gx  = gx0 + col - 1;
            l = (unsigned)((ci * ROWS + row) * RLEN + col);
            if ((unsigned)gy < (unsigned)HH && (unsigned)gx < (unsigned)WW)
                g = (unsigned)(ci * (HH * WW) + gy * WW + gx);
        }
        goff[k] = g;
        if (k & 1) loff[k >> 1] |= (l << 16); else loff[k >> 1] = l;
    }

    float val[NIT];

// Issue the staging loads for timestep TT into val[] (non-blocking; invalid
// elements clamp to offset 0 and cndmask to 0).
#define LOADV(TT) {                                                                   \
        const float* xsrc = x + ((size_t)((TT) * BATCH + b) * C_IN) * (HH * WW);      \
        _Pragma("unroll")                                                             \
        for (int k = 0; k < NIT; ++k) {                                               \
            unsigned g = goff[k];                                                     \
            float vv = xsrc[g & 0x7FFFFFFFu];                                         \
            val[k] = ((int)g >= 0) ? vv : 0.0f;                                       \
        }                                                                             \
    }

#define WRITEV() {                                                                    \
        float* sf = &sx[0][0][0];                                                     \
        _Pragma("unroll")                                                             \
        for (int k = 0; k < NIT; ++k) {                                               \
            unsigned l = (k & 1) ? (loff[k >> 1] >> 16) : (loff[k >> 1] & 0xFFFFu);   \
            sf[l] = val[k];                                                           \
        }                                                                             \
    }

    float v[16];
#pragma unroll
    for (int o = 0; o < 16; ++o) v[o] = 0.0f;

    // prologue: stage t=0
    LOADV(0);
    WRITEV();
    __syncthreads();

    for (int t = 0; t < T_STEPS; ++t) {
        if (t < T_STEPS - 1) LOADV(t + 1);   // in flight under the compute phase

        float acc[16];
#pragma unroll
        for (int o = 0; o < 16; ++o) acc[o] = 0.0f;

// One conv tap: ci 0..63 sequential (exact chain order). One ds_read_b32 per
// ci, 16 FMAs with SGPR-broadcast weights (wave-uniform s_load).
#define TAP(KY, KX)                                                                   \
        {                                                                             \
            const float* wj = wt + ((KY) * 3 + (KX)) * (C_IN * C_OUT) + cob;          \
            _Pragma("unroll 4")                                                       \
            for (int ci = 0; ci < C_IN; ++ci) {                                       \
                const float xv = sx[ci][sy + y + (KY)][xcol + (KX)];                  \
                const float* wp = wj + (ci << 6);                                     \
                _Pragma("unroll")                                                     \
                for (int o = 0; o < 16; ++o)                                          \
                    acc[o] = fmaf(xv, wp[o], acc[o]);                                 \
            }                                                                         \
        }

        TAP(0, 0) TAP(0, 1) TAP(0, 2)
        TAP(1, 0) TAP(1, 1) TAP(1, 2)
        TAP(2, 0) TAP(2, 1) TAP(2, 2)
#undef TAP

        // ---- LIF update (exact f32 op sequence) + spike store ----
        float* obase = out + ((size_t)(t * BATCH + b) * C_OUT + cob) * (HH * WW)
                     + (gy0 + sy + y) * WW + gx0 + xcol;
#pragma unroll
        for (int o = 0; o < 16; ++o) {
            float cb = __fadd_rn(acc[o], bp[o]);                  // conv + bias (SGPR)
            float vt = __fadd_rn(__fmul_rn(v[o], DECAY_F32), cb); // v*DECAY + cb
            bool fire = vt > 1.0f;
            v[o] = fire ? 0.0f : vt;                              // soft reset
            obase[(size_t)o * (HH * WW)] = fire ? 1.0f : 0.0f;
        }

        if (t < T_STEPS - 1) {
            __syncthreads();   // all reads of sx done
            WRITEV();          // ds_write next t (vmcnt waits inserted per value)
            __syncthreads();   // sx ready
        }
    }
#undef LOADV
#undef WRITEV
}

extern "C" void kernel_launch(void* const* d_in, const int* in_sizes, int n_in,
                              void* d_out, int out_size, void* d_ws, size_t ws_size,
                              hipStream_t stream) {
    const float* x    = (const float*)d_in[0];
    const float* w    = (const float*)d_in[1];
    const float* bias = (const float*)d_in[2];
    float* out = (float*)d_out;
    float* wt  = (float*)d_ws;   // 9*64*64*4 = 147456 bytes

    hipLaunchKernelGGL(wt_build_kernel, dim3((9 * C_IN * C_OUT + 255) / 256), dim3(256), 0, stream, w, wt);
    hipLaunchKernelGGL(snn_exact_kernel, dim3(WW / TW, HH / TH, BATCH), dim3(512), 0, stream,
                       x, wt, bias, out);
}